// Round 4
// baseline (161.731 us; speedup 1.0000x reference)
//
#include <hip/hip_runtime.h>

#define N_NODES 65536
#define N_FEAT  64
#define N_HEADS 4
#define BATCHSZ 131072
#define NTYPE   4
#define ALPHA   0.2f
#define SRC_PER_NODE 8   // (BATCHSZ*NTYPE)/N_NODES, guaranteed by construction

// ---------------- Pass 1: inverse index build ----------------
// For each flat batch entry u (= b*NTYPE + i), target node t = batch[u].
// Record u in idx[t*8 + pos].
__global__ __launch_bounds__(256) void build_index(const int* __restrict__ batch,
                                                   int* __restrict__ cnt,
                                                   int* __restrict__ idx) {
    int u = blockIdx.x * blockDim.x + threadIdx.x;  // 0 .. BATCHSZ*NTYPE-1
    int t = batch[u];
    int pos = atomicAdd(&cnt[t], 1);
    if (pos < SRC_PER_NODE) idx[t * SRC_PER_NODE + pos] = u;
}

// ---------------- Pass 2: gather + head-mix + max + epilogue ----------------
// One wave (64 lanes) per node; lane = feature index f.
// For each of the node's 8 source rows (b,i): neighbors are batch[b][j], j!=i,
// ascending j (matches cols[i] in the reference). Head a value:
//   v_a[f] = sum_k w[a][k] * feat[n_k][f];  m_a[f] = max over sources.
// out[t, a*64+f] = leaky_relu(feat[t][f] + m_a[f]).
__global__ __launch_bounds__(256) void gat_agg(const int* __restrict__ batch,
                                               const float* __restrict__ feat,
                                               const float* __restrict__ att,
                                               const int* __restrict__ idx,
                                               float* __restrict__ out) {
    const int wave = threadIdx.x >> 6;
    const int lane = threadIdx.x & 63;
    const int t = blockIdx.x * 4 + wave;

    // attention weights -> registers (tiny, broadcast from cache)
    float w[N_HEADS][3];
    #pragma unroll
    for (int a = 0; a < N_HEADS; ++a)
        #pragma unroll
        for (int k = 0; k < 3; ++k)
            w[a][k] = att[a * 3 + k];

    const int4* batch4 = (const int4*)batch;

    // load the 8 source codes up-front (two int4 loads, wave-uniform addr)
    const int4* ip = (const int4*)(idx + t * SRC_PER_NODE);
    int4 s0 = ip[0];
    int4 s1 = ip[1];
    int src[SRC_PER_NODE] = {s0.x, s0.y, s0.z, s0.w, s1.x, s1.y, s1.z, s1.w};

    float m[N_HEADS];
    #pragma unroll
    for (int a = 0; a < N_HEADS; ++a) m[a] = -INFINITY;

    #pragma unroll
    for (int s = 0; s < SRC_PER_NODE; ++s) {
        int u = src[s];
        int b = u >> 2;
        int i = u & 3;
        int4 br = batch4[b];
        // cols[i] = ascending j != i
        int n0 = (i == 0) ? br.y : br.x;
        int n1 = (i <= 1) ? br.z : br.y;
        int n2 = (i <= 2) ? br.w : br.z;
        float f0 = feat[n0 * N_FEAT + lane];   // coalesced 256B row read
        float f1 = feat[n1 * N_FEAT + lane];
        float f2 = feat[n2 * N_FEAT + lane];
        #pragma unroll
        for (int a = 0; a < N_HEADS; ++a) {
            float v = fmaf(w[a][0], f0, fmaf(w[a][1], f1, w[a][2] * f2));
            m[a] = fmaxf(m[a], v);
        }
    }

    float x = feat[t * N_FEAT + lane];
    #pragma unroll
    for (int a = 0; a < N_HEADS; ++a) {
        float o = x + m[a];
        o = fmaxf(o, ALPHA * o);   // leaky_relu for slope<1, branchless
        out[t * (N_HEADS * N_FEAT) + a * N_FEAT + lane] = o;
    }
}

extern "C" void kernel_launch(void* const* d_in, const int* in_sizes, int n_in,
                              void* d_out, int out_size, void* d_ws, size_t ws_size,
                              hipStream_t stream) {
    const int*   batch = (const int*)d_in[0];    // [BATCHSZ, NTYPE] int32
    const float* feat  = (const float*)d_in[1];  // [N_NODES, N_FEAT] f32
    const float* att   = (const float*)d_in[2];  // [N_HEADS, NTYPE-1] f32
    float* out = (float*)d_out;                  // [N_NODES, N_HEADS*N_FEAT] f32

    int* cnt = (int*)d_ws;                       // [N_NODES]
    int* idx = cnt + N_NODES;                    // [N_NODES * 8]

    // counters must be zero every launch (ws is poisoned 0xAA)
    hipMemsetAsync(cnt, 0, N_NODES * sizeof(int), stream);

    build_index<<<(BATCHSZ * NTYPE) / 256, 256, 0, stream>>>(batch, cnt, idx);
    gat_agg<<<N_NODES / 4, 256, 0, stream>>>(batch, feat, att, idx, out);
}